// Round 1
// baseline (1720.233 us; speedup 1.0000x reference)
//
#include <hip/hip_runtime.h>
#include <math.h>

#define NN   20000
#define NE   640000
#define HD   128
#define EDIM 16
#define KIN  273   // 2H + 1 + ED

__device__ __forceinline__ float silu_f(float v) {
    return v / (1.0f + expf(-v));
}

// -------------------- Edge kernel --------------------
// 256 threads, 64 edges per block. Each thread owns a 4-edge x 8-channel tile.
// LDS ~76 KB -> 2 blocks/CU.
__global__ __launch_bounds__(256, 2) void egnn_edge_kernel(
    const float* __restrict__ h, const float* __restrict__ x,
    const int* __restrict__ ei, const float* __restrict__ eattr,
    const float* __restrict__ We1, const float* __restrict__ be1,
    const float* __restrict__ We2, const float* __restrict__ be2,
    const float* __restrict__ Wx1, const float* __restrict__ bx1,
    const float* __restrict__ Wx2, const float* __restrict__ bx2,
    float* __restrict__ msg_agg, float* __restrict__ coord_agg)
{
    __shared__ float sT[64][HD + 4];   // silu(e_in@We1+be1)
    __shared__ float sM[64][HD + 4];   // m_ij
    __shared__ float eA[64][33];       // e_in k-chunk; reused as reduction buf
    __shared__ int   sSrc[64], sDst[64];
    __shared__ float sDiff[64][3];
    __shared__ float sDist[64];
    __shared__ float sW[64];           // coord_w per edge

    const int t  = threadIdx.x;
    const int e0 = blockIdx.x * 64;

    if (t < 64) {
        const int e = e0 + t;
        const int s = ei[e];
        const int d = ei[NE + e];
        sSrc[t] = s; sDst[t] = d;
        const float dx = x[s*3+0] - x[d*3+0];
        const float dy = x[s*3+1] - x[d*3+1];
        const float dz = x[s*3+2] - x[d*3+2];
        sDiff[t][0] = dx; sDiff[t][1] = dy; sDiff[t][2] = dz;
        sDist[t] = (dx*dx + dy*dy + dz*dz) * 0.01f;
    }
    __syncthreads();

    const int c   = t & 15;   // channel group: ch0..ch0+7
    const int r   = t >> 4;   // edge group: eb..eb+3
    const int ch0 = c * 8;
    const int eb  = r * 4;
    const int eL  = t >> 2;   // edge for cooperative e_in build
    const int q   = t & 3;    // k-quad within build
    const int kq0 = q * 8;

    float acc[4][8];
    #pragma unroll
    for (int i = 0; i < 4; ++i)
        #pragma unroll
        for (int j = 0; j < 8; ++j) acc[i][j] = 0.0f;

    // ---- GEMM1: e_in[273] @ We1[273,128], k-chunks of 32 ----
    for (int chunk = 0; chunk < 9; ++chunk) {
        __syncthreads();   // previous chunk's readers done before overwrite
        if (chunk < 4) {
            const float4* p = reinterpret_cast<const float4*>(
                h + (size_t)sSrc[eL]*HD + chunk*32 + kq0);
            const float4 v0 = p[0], v1 = p[1];
            float* dp = &eA[eL][kq0];
            dp[0]=v0.x; dp[1]=v0.y; dp[2]=v0.z; dp[3]=v0.w;
            dp[4]=v1.x; dp[5]=v1.y; dp[6]=v1.z; dp[7]=v1.w;
        } else if (chunk < 8) {
            const float4* p = reinterpret_cast<const float4*>(
                h + (size_t)sDst[eL]*HD + (chunk-4)*32 + kq0);
            const float4 v0 = p[0], v1 = p[1];
            float* dp = &eA[eL][kq0];
            dp[0]=v0.x; dp[1]=v0.y; dp[2]=v0.z; dp[3]=v0.w;
            dp[4]=v1.x; dp[5]=v1.y; dp[6]=v1.z; dp[7]=v1.w;
        } else {
            #pragma unroll
            for (int jj = 0; jj < 8; ++jj) {
                const int kg = 256 + kq0 + jj;
                float v = 0.0f;
                if (kg == 256)      v = sDist[eL];
                else if (kg < KIN)  v = eattr[(size_t)(e0+eL)*EDIM + (kg-257)];
                eA[eL][kq0+jj] = v;
            }
        }
        __syncthreads();
        const int kmax = (chunk == 8) ? 17 : 32;
        const int kb   = chunk * 32;
        #pragma unroll 4
        for (int kk = 0; kk < kmax; ++kk) {
            const float4* wp = reinterpret_cast<const float4*>(
                We1 + (size_t)(kb+kk)*HD + ch0);
            const float4 b0 = wp[0], b1 = wp[1];
            const float bb[8] = {b0.x,b0.y,b0.z,b0.w,b1.x,b1.y,b1.z,b1.w};
            #pragma unroll
            for (int i = 0; i < 4; ++i) {
                const float a = eA[eb+i][kk];
                #pragma unroll
                for (int j = 0; j < 8; ++j) acc[i][j] += a * bb[j];
            }
        }
    }

    // t1 = silu(acc + be1) -> sT
    {
        const float4* bp = reinterpret_cast<const float4*>(be1 + ch0);
        const float4 c0v = bp[0], c1v = bp[1];
        const float bias[8] = {c0v.x,c0v.y,c0v.z,c0v.w,c1v.x,c1v.y,c1v.z,c1v.w};
        #pragma unroll
        for (int i = 0; i < 4; ++i)
            #pragma unroll
            for (int j = 0; j < 8; ++j)
                sT[eb+i][ch0+j] = silu_f(acc[i][j] + bias[j]);
    }
    __syncthreads();

    // ---- GEMM2: t1 @ We2 ----
    #pragma unroll
    for (int i = 0; i < 4; ++i)
        #pragma unroll
        for (int j = 0; j < 8; ++j) acc[i][j] = 0.0f;
    #pragma unroll 4
    for (int kk = 0; kk < HD; ++kk) {
        const float4* wp = reinterpret_cast<const float4*>(
            We2 + (size_t)kk*HD + ch0);
        const float4 b0 = wp[0], b1 = wp[1];
        const float bb[8] = {b0.x,b0.y,b0.z,b0.w,b1.x,b1.y,b1.z,b1.w};
        #pragma unroll
        for (int i = 0; i < 4; ++i) {
            const float a = sT[eb+i][kk];
            #pragma unroll
            for (int j = 0; j < 8; ++j) acc[i][j] += a * bb[j];
        }
    }
    // m_ij = silu(acc + be2) -> sM
    {
        const float4* bp = reinterpret_cast<const float4*>(be2 + ch0);
        const float4 c0v = bp[0], c1v = bp[1];
        const float bias[8] = {c0v.x,c0v.y,c0v.z,c0v.w,c1v.x,c1v.y,c1v.z,c1v.w};
        #pragma unroll
        for (int i = 0; i < 4; ++i)
            #pragma unroll
            for (int j = 0; j < 8; ++j)
                sM[eb+i][ch0+j] = silu_f(acc[i][j] + bias[j]);
    }
    __syncthreads();

    // ---- GEMM3: m_ij @ Wx1, then dot with Wx2 -> coord_w ----
    #pragma unroll
    for (int i = 0; i < 4; ++i)
        #pragma unroll
        for (int j = 0; j < 8; ++j) acc[i][j] = 0.0f;
    #pragma unroll 4
    for (int kk = 0; kk < HD; ++kk) {
        const float4* wp = reinterpret_cast<const float4*>(
            Wx1 + (size_t)kk*HD + ch0);
        const float4 b0 = wp[0], b1 = wp[1];
        const float bb[8] = {b0.x,b0.y,b0.z,b0.w,b1.x,b1.y,b1.z,b1.w};
        #pragma unroll
        for (int i = 0; i < 4; ++i) {
            const float a = sM[eb+i][kk];
            #pragma unroll
            for (int j = 0; j < 8; ++j) acc[i][j] += a * bb[j];
        }
    }
    float part[4] = {0.0f, 0.0f, 0.0f, 0.0f};
    {
        const float4* bp = reinterpret_cast<const float4*>(bx1 + ch0);
        const float4 c0v = bp[0], c1v = bp[1];
        const float bias[8] = {c0v.x,c0v.y,c0v.z,c0v.w,c1v.x,c1v.y,c1v.z,c1v.w};
        const float4* xp = reinterpret_cast<const float4*>(Wx2 + ch0);
        const float4 x0v = xp[0], x1v = xp[1];
        const float wx[8] = {x0v.x,x0v.y,x0v.z,x0v.w,x1v.x,x1v.y,x1v.z,x1v.w};
        #pragma unroll
        for (int i = 0; i < 4; ++i)
            #pragma unroll
            for (int j = 0; j < 8; ++j)
                part[i] += silu_f(acc[i][j] + bias[j]) * wx[j];
    }
    __syncthreads();
    float* red = &eA[0][0];   // reuse (eA dead since GEMM1)
    #pragma unroll
    for (int i = 0; i < 4; ++i) red[(eb+i)*16 + c] = part[i];
    __syncthreads();
    if (t < 64) {
        float s = 0.0f;
        #pragma unroll
        for (int cc = 0; cc < 16; ++cc) s += red[t*16 + cc];
        sW[t] = tanhf(s + bx2[0]);
    }
    __syncthreads();

    // ---- scatter: msg_agg += m_ij, coord_agg += diff * coord_w ----
    #pragma unroll
    for (int it = 0; it < 32; ++it) {
        const int idx = t + it * 256;
        const int e   = idx >> 7;
        const int ch  = idx & 127;
        atomicAdd(&msg_agg[(size_t)sDst[e]*HD + ch], sM[e][ch]);
    }
    if (t < 192) {
        const int e  = t / 3;
        const int d3 = t - e*3;
        atomicAdd(&coord_agg[(size_t)sDst[e]*3 + d3], sDiff[e][d3] * sW[e]);
    }
}

// -------------------- Node kernel --------------------
__global__ __launch_bounds__(256, 4) void egnn_node_kernel(
    const float* __restrict__ h, const float* __restrict__ x,
    const int* __restrict__ fixed_mask,
    const float* __restrict__ Wh1, const float* __restrict__ bh1,
    const float* __restrict__ Wh2, const float* __restrict__ bh2,
    const float* __restrict__ msg_agg, const float* __restrict__ coord_agg,
    float* __restrict__ out_h, float* __restrict__ out_x)
{
    __shared__ float sT[64][HD + 4];
    const int t  = threadIdx.x;
    const int n0 = blockIdx.x * 64;
    const int c = t & 15, r = t >> 4;
    const int ch0 = c * 8, nb = r * 4;

    // x_new = x + (~fixed) * coord_agg
    if (t < 192) {
        const int ln = t / 3, d3 = t - ln*3;
        const int n  = n0 + ln;
        if (n < NN) {
            const float add = (fixed_mask[n] != 0) ? 0.0f : coord_agg[(size_t)n*3 + d3];
            out_x[(size_t)n*3 + d3] = x[(size_t)n*3 + d3] + add;
        }
    }

    int nidx[4];
    #pragma unroll
    for (int i = 0; i < 4; ++i) nidx[i] = min(n0 + nb + i, NN - 1);

    float acc[4][8];
    #pragma unroll
    for (int i = 0; i < 4; ++i)
        #pragma unroll
        for (int j = 0; j < 8; ++j) acc[i][j] = 0.0f;

    // GEMM1: concat[h,msg] @ Wh1 (k = 0..255)
    #pragma unroll 4
    for (int kk = 0; kk < 2*HD; ++kk) {
        const float4* wp = reinterpret_cast<const float4*>(
            Wh1 + (size_t)kk*HD + ch0);
        const float4 b0 = wp[0], b1 = wp[1];
        const float bb[8] = {b0.x,b0.y,b0.z,b0.w,b1.x,b1.y,b1.z,b1.w};
        #pragma unroll
        for (int i = 0; i < 4; ++i) {
            const float a = (kk < HD) ? h[(size_t)nidx[i]*HD + kk]
                                      : msg_agg[(size_t)nidx[i]*HD + (kk - HD)];
            #pragma unroll
            for (int j = 0; j < 8; ++j) acc[i][j] += a * bb[j];
        }
    }
    {
        const float4* bp = reinterpret_cast<const float4*>(bh1 + ch0);
        const float4 c0v = bp[0], c1v = bp[1];
        const float bias[8] = {c0v.x,c0v.y,c0v.z,c0v.w,c1v.x,c1v.y,c1v.z,c1v.w};
        #pragma unroll
        for (int i = 0; i < 4; ++i)
            #pragma unroll
            for (int j = 0; j < 8; ++j)
                sT[nb+i][ch0+j] = silu_f(acc[i][j] + bias[j]);
    }
    __syncthreads();

    // GEMM2: sT @ Wh2, out_h = h + acc + bh2
    #pragma unroll
    for (int i = 0; i < 4; ++i)
        #pragma unroll
        for (int j = 0; j < 8; ++j) acc[i][j] = 0.0f;
    #pragma unroll 4
    for (int kk = 0; kk < HD; ++kk) {
        const float4* wp = reinterpret_cast<const float4*>(
            Wh2 + (size_t)kk*HD + ch0);
        const float4 b0 = wp[0], b1 = wp[1];
        const float bb[8] = {b0.x,b0.y,b0.z,b0.w,b1.x,b1.y,b1.z,b1.w};
        #pragma unroll
        for (int i = 0; i < 4; ++i) {
            const float a = sT[nb+i][kk];
            #pragma unroll
            for (int j = 0; j < 8; ++j) acc[i][j] += a * bb[j];
        }
    }
    {
        const float4* bp = reinterpret_cast<const float4*>(bh2 + ch0);
        const float4 c0v = bp[0], c1v = bp[1];
        const float bias[8] = {c0v.x,c0v.y,c0v.z,c0v.w,c1v.x,c1v.y,c1v.z,c1v.w};
        #pragma unroll
        for (int i = 0; i < 4; ++i) {
            const int n = n0 + nb + i;
            if (n < NN) {
                #pragma unroll
                for (int j = 0; j < 8; ++j)
                    out_h[(size_t)n*HD + ch0 + j] =
                        h[(size_t)n*HD + ch0 + j] + acc[i][j] + bias[j];
            }
        }
    }
}

extern "C" void kernel_launch(void* const* d_in, const int* in_sizes, int n_in,
                              void* d_out, int out_size, void* d_ws, size_t ws_size,
                              hipStream_t stream)
{
    const float* h     = (const float*)d_in[0];
    const float* x     = (const float*)d_in[1];
    const int*   ei    = (const int*)d_in[2];
    const float* eattr = (const float*)d_in[3];
    const int*   fmask = (const int*)d_in[4];
    const float* We1   = (const float*)d_in[5];
    const float* be1   = (const float*)d_in[6];
    const float* We2   = (const float*)d_in[7];
    const float* be2   = (const float*)d_in[8];
    const float* Wx1   = (const float*)d_in[9];
    const float* bx1   = (const float*)d_in[10];
    const float* Wx2   = (const float*)d_in[11];
    const float* bx2   = (const float*)d_in[12];
    const float* Wh1   = (const float*)d_in[13];
    const float* bh1   = (const float*)d_in[14];
    const float* Wh2   = (const float*)d_in[15];
    const float* bh2   = (const float*)d_in[16];

    float* msg   = (float*)d_ws;                 // [NN, HD]
    float* coord = msg + (size_t)NN * HD;        // [NN, 3]
    float* out_h = (float*)d_out;                // [NN, HD]
    float* out_x = out_h + (size_t)NN * HD;      // [NN, 3]

    hipMemsetAsync(d_ws, 0, (size_t)NN * (HD + 3) * sizeof(float), stream);
    egnn_edge_kernel<<<NE / 64, 256, 0, stream>>>(
        h, x, ei, eattr, We1, be1, We2, be2, Wx1, bx1, Wx2, bx2, msg, coord);
    egnn_node_kernel<<<(NN + 63) / 64, 256, 0, stream>>>(
        h, x, fmask, Wh1, bh1, Wh2, bh2, msg, coord, out_h, out_x);
}

// Round 2
// 589.848 us; speedup vs baseline: 2.9164x; 2.9164x over previous
//
#include <hip/hip_runtime.h>
#include <hip/hip_bf16.h>
#include <math.h>

#define NN   20000
#define NE   640000
#define HD   128
#define EDIM 16
#define KIN  273    // 2H + 1 + ED
#define KP1  288    // KIN padded to 9*32
#define P1   296    // e_in LDS pitch (ushorts): 592 B = 37*16B, odd groups
#define P2   136    // t1/m LDS pitch (ushorts): 272 B = 17*16B

typedef __bf16 bf16x8 __attribute__((ext_vector_type(8)));
typedef float  f32x4  __attribute__((ext_vector_type(4)));

__device__ __forceinline__ float silu_f(float v) { return v / (1.0f + expf(-v)); }

__device__ __forceinline__ unsigned short f2bf(float f) {
    __bf16 b = (__bf16)f;
    return __builtin_bit_cast(unsigned short, b);
}
__device__ __forceinline__ float bf2f(unsigned short u) {
    __bf16 b = __builtin_bit_cast(__bf16, u);
    return (float)b;
}

// -------------------- Prep: h->bf16, pack W into MFMA B-frag order ----------
// B-frag for tile (kb,nb): elem[lane*8+j] = W[kb*32+(lane>>4)*8+j][nb*16+(lane&15)]
__device__ __forceinline__ void pack_one(const float* __restrict__ W, int Kreal,
                                         unsigned short* __restrict__ P, int idx) {
    const int f    = idx >> 9;       // tile
    const int r    = idx & 511;
    const int lane = r >> 3;
    const int j    = r & 7;
    const int kb   = f >> 3;
    const int nb   = f & 7;
    const int k    = kb * 32 + (lane >> 4) * 8 + j;
    const int n    = nb * 16 + (lane & 15);
    const float v  = (k < Kreal) ? W[(size_t)k * HD + n] : 0.0f;
    P[idx] = f2bf(v);
}

__global__ void egnn_prep_kernel(
    const float* __restrict__ h,
    const float* __restrict__ We1, const float* __restrict__ We2,
    const float* __restrict__ Wx1,
    unsigned short* __restrict__ hb,
    unsigned short* __restrict__ PWe1, unsigned short* __restrict__ PWe2,
    unsigned short* __restrict__ PWx1)
{
    const size_t NH = (size_t)NN * HD;          // 2,560,000
    const size_t S1 = (size_t)(KP1 / 32) * 8 * 512;   // 36864
    const size_t S2 = (size_t)4 * 8 * 512;            // 16384
    const size_t S3 = S2;
    const size_t total  = NH + S1 + S2 + S3;
    const size_t stride = (size_t)gridDim.x * blockDim.x;
    for (size_t i = (size_t)blockIdx.x * blockDim.x + threadIdx.x; i < total; i += stride) {
        if (i < NH) {
            hb[i] = f2bf(h[i]);
        } else if (i < NH + S1) {
            pack_one(We1, KIN, PWe1, (int)(i - NH));
        } else if (i < NH + S1 + S2) {
            pack_one(We2, HD, PWe2, (int)(i - NH - S1));
        } else {
            pack_one(Wx1, HD, PWx1, (int)(i - NH - S1 - S2));
        }
    }
}

// -------------------- Edge kernel (MFMA) --------------------
// 256 threads = 4 waves, 64 edges/block. Wave w computes M=64 x N=[w*32,w*32+32).
__global__ __launch_bounds__(256, 2) void egnn_edge_kernel(
    const unsigned short* __restrict__ hb, const float* __restrict__ x,
    const int* __restrict__ ei, const float* __restrict__ eattr,
    const unsigned short* __restrict__ PWe1, const float* __restrict__ be1,
    const unsigned short* __restrict__ PWe2, const float* __restrict__ be2,
    const unsigned short* __restrict__ PWx1, const float* __restrict__ bx1,
    const float* __restrict__ Wx2, const float* __restrict__ bx2,
    float* __restrict__ msg_agg, float* __restrict__ coord_agg)
{
    __shared__ __align__(16) unsigned short eA[64 * P1];   // e_in bf16, 37888 B
    __shared__ __align__(16) unsigned short sT[64 * P2];   // t1 bf16,   17408 B
    __shared__ __align__(16) unsigned short sM[64 * P2];   // m_ij bf16, 17408 B
    __shared__ int   sSrc[64], sDst[64];
    __shared__ float sDiff[64][3];
    __shared__ float sDist[64];
    __shared__ float sW[64];

    const int t  = threadIdx.x;
    const int e0 = blockIdx.x * 64;

    if (t < 64) {
        const int e = e0 + t;
        const int s = ei[e];
        const int d = ei[NE + e];
        sSrc[t] = s; sDst[t] = d;
        const float dx = x[s*3+0] - x[d*3+0];
        const float dy = x[s*3+1] - x[d*3+1];
        const float dz = x[s*3+2] - x[d*3+2];
        sDiff[t][0] = dx; sDiff[t][1] = dy; sDiff[t][2] = dz;
        sDist[t] = (dx*dx + dy*dy + dz*dz) * 0.01f;
    }
    __syncthreads();

    // ---- build e_in (bf16) in LDS: [64][P1], cols 0..287 (273..287 = 0) ----
    {
        const int eL = t >> 2, q = t & 3;
        const unsigned short* hs = hb + (size_t)sSrc[eL] * HD + q * 32;
        const unsigned short* hd = hb + (size_t)sDst[eL] * HD + q * 32;
        uint4* dsts = (uint4*)&eA[eL * P1 + q * 32];
        uint4* dstd = (uint4*)&eA[eL * P1 + 128 + q * 32];
        #pragma unroll
        for (int v = 0; v < 4; ++v) dsts[v] = ((const uint4*)hs)[v];
        #pragma unroll
        for (int v = 0; v < 4; ++v) dstd[v] = ((const uint4*)hd)[v];
        #pragma unroll
        for (int jj = 0; jj < 8; ++jj) {
            const int kg = 256 + q * 8 + jj;
            float v = 0.0f;
            if (kg == 256)     v = sDist[eL];
            else if (kg < KIN) v = eattr[(size_t)(e0 + eL) * EDIM + (kg - 257)];
            eA[eL * P1 + kg] = f2bf(v);
        }
    }
    __syncthreads();

    const int lane = t & 63;
    const int w    = t >> 6;
    const int quad = lane >> 4;
    const int l16  = lane & 15;

    // ---- GEMM1: e_in[64,288] @ We1 -> acc1 (wave's 32 cols) ----
    f32x4 acc1[4][2];
    #pragma unroll
    for (int mb = 0; mb < 4; ++mb)
        #pragma unroll
        for (int nt = 0; nt < 2; ++nt) acc1[mb][nt] = (f32x4){0.f,0.f,0.f,0.f};

    for (int kb = 0; kb < 9; ++kb) {
        bf16x8 a[4], b[2];
        #pragma unroll
        for (int mb = 0; mb < 4; ++mb)
            a[mb] = *(const bf16x8*)&eA[(mb * 16 + l16) * P1 + kb * 32 + quad * 8];
        #pragma unroll
        for (int nt = 0; nt < 2; ++nt) {
            const int nb = w * 2 + nt;
            b[nt] = *(const bf16x8*)&PWe1[((kb * 8 + nb) * 64 + lane) * 8];
        }
        #pragma unroll
        for (int mb = 0; mb < 4; ++mb)
            #pragma unroll
            for (int nt = 0; nt < 2; ++nt)
                acc1[mb][nt] = __builtin_amdgcn_mfma_f32_16x16x32_bf16(
                    a[mb], b[nt], acc1[mb][nt], 0, 0, 0);
    }
    // t1 = silu(acc1 + be1) -> sT (bf16)
    #pragma unroll
    for (int nt = 0; nt < 2; ++nt) {
        const int col = (w * 2 + nt) * 16 + l16;
        const float bias = be1[col];
        #pragma unroll
        for (int mb = 0; mb < 4; ++mb)
            #pragma unroll
            for (int r = 0; r < 4; ++r) {
                const int row = mb * 16 + quad * 4 + r;
                sT[row * P2 + col] = f2bf(silu_f(acc1[mb][nt][r] + bias));
            }
    }
    __syncthreads();

    // ---- GEMM2: t1[64,128] @ We2 -> m_ij ----
    f32x4 acc2[4][2];
    #pragma unroll
    for (int mb = 0; mb < 4; ++mb)
        #pragma unroll
        for (int nt = 0; nt < 2; ++nt) acc2[mb][nt] = (f32x4){0.f,0.f,0.f,0.f};
    for (int kb = 0; kb < 4; ++kb) {
        bf16x8 a[4], b[2];
        #pragma unroll
        for (int mb = 0; mb < 4; ++mb)
            a[mb] = *(const bf16x8*)&sT[(mb * 16 + l16) * P2 + kb * 32 + quad * 8];
        #pragma unroll
        for (int nt = 0; nt < 2; ++nt) {
            const int nb = w * 2 + nt;
            b[nt] = *(const bf16x8*)&PWe2[((kb * 8 + nb) * 64 + lane) * 8];
        }
        #pragma unroll
        for (int mb = 0; mb < 4; ++mb)
            #pragma unroll
            for (int nt = 0; nt < 2; ++nt)
                acc2[mb][nt] = __builtin_amdgcn_mfma_f32_16x16x32_bf16(
                    a[mb], b[nt], acc2[mb][nt], 0, 0, 0);
    }
    #pragma unroll
    for (int nt = 0; nt < 2; ++nt) {
        const int col = (w * 2 + nt) * 16 + l16;
        const float bias = be2[col];
        #pragma unroll
        for (int mb = 0; mb < 4; ++mb)
            #pragma unroll
            for (int r = 0; r < 4; ++r) {
                const int row = mb * 16 + quad * 4 + r;
                sM[row * P2 + col] = f2bf(silu_f(acc2[mb][nt][r] + bias));
            }
    }
    __syncthreads();

    // ---- msg scatter first (fire-and-forget atomics overlap GEMM3) ----
    #pragma unroll
    for (int it = 0; it < 32; ++it) {
        const int idx = t + it * 256;
        const int e   = idx >> 7;
        const int ch  = idx & 127;
        atomicAdd(&msg_agg[(size_t)sDst[e] * HD + ch], bf2f(sM[e * P2 + ch]));
    }

    // ---- GEMM3: m_ij @ Wx1, then silu(+bx1) dot Wx2 per edge ----
    f32x4 acc3[4][2];
    #pragma unroll
    for (int mb = 0; mb < 4; ++mb)
        #pragma unroll
        for (int nt = 0; nt < 2; ++nt) acc3[mb][nt] = (f32x4){0.f,0.f,0.f,0.f};
    for (int kb = 0; kb < 4; ++kb) {
        bf16x8 a[4], b[2];
        #pragma unroll
        for (int mb = 0; mb < 4; ++mb)
            a[mb] = *(const bf16x8*)&sM[(mb * 16 + l16) * P2 + kb * 32 + quad * 8];
        #pragma unroll
        for (int nt = 0; nt < 2; ++nt) {
            const int nb = w * 2 + nt;
            b[nt] = *(const bf16x8*)&PWx1[((kb * 8 + nb) * 64 + lane) * 8];
        }
        #pragma unroll
        for (int mb = 0; mb < 4; ++mb)
            #pragma unroll
            for (int nt = 0; nt < 2; ++nt)
                acc3[mb][nt] = __builtin_amdgcn_mfma_f32_16x16x32_bf16(
                    a[mb], b[nt], acc3[mb][nt], 0, 0, 0);
    }
    // partial dot with Wx2 -> pRed[row][w*16+l16] (reuse eA as fp32 [64][68])
    {
        float* pRed = reinterpret_cast<float*>(eA);
        float bias[2], wx[2];
        #pragma unroll
        for (int nt = 0; nt < 2; ++nt) {
            const int col = (w * 2 + nt) * 16 + l16;
            bias[nt] = bx1[col];
            wx[nt]   = Wx2[col];
        }
        #pragma unroll
        for (int mb = 0; mb < 4; ++mb)
            #pragma unroll
            for (int r = 0; r < 4; ++r) {
                const int row = mb * 16 + quad * 4 + r;
                float p = 0.0f;
                #pragma unroll
                for (int nt = 0; nt < 2; ++nt)
                    p += silu_f(acc3[mb][nt][r] + bias[nt]) * wx[nt];
                pRed[row * 68 + w * 16 + l16] = p;
            }
    }
    __syncthreads();
    if (t < 64) {
        const float* pRed = reinterpret_cast<const float*>(eA);
        float s = bx2[0];
        #pragma unroll 8
        for (int cc = 0; cc < 64; ++cc) s += pRed[t * 68 + cc];
        sW[t] = tanhf(s);
    }
    __syncthreads();

    if (t < 192) {
        const int e  = t / 3;
        const int d3 = t - e * 3;
        atomicAdd(&coord_agg[(size_t)sDst[e] * 3 + d3], sDiff[e][d3] * sW[e]);
    }
}

// -------------------- Node kernel (fp32, unchanged) --------------------
__global__ __launch_bounds__(256, 4) void egnn_node_kernel(
    const float* __restrict__ h, const float* __restrict__ x,
    const int* __restrict__ fixed_mask,
    const float* __restrict__ Wh1, const float* __restrict__ bh1,
    const float* __restrict__ Wh2, const float* __restrict__ bh2,
    const float* __restrict__ msg_agg, const float* __restrict__ coord_agg,
    float* __restrict__ out_h, float* __restrict__ out_x)
{
    __shared__ float sT[64][HD + 4];
    const int t  = threadIdx.x;
    const int n0 = blockIdx.x * 64;
    const int c = t & 15, r = t >> 4;
    const int ch0 = c * 8, nb = r * 4;

    if (t < 192) {
        const int ln = t / 3, d3 = t - ln * 3;
        const int n  = n0 + ln;
        if (n < NN) {
            const float add = (fixed_mask[n] != 0) ? 0.0f : coord_agg[(size_t)n*3 + d3];
            out_x[(size_t)n*3 + d3] = x[(size_t)n*3 + d3] + add;
        }
    }

    int nidx[4];
    #pragma unroll
    for (int i = 0; i < 4; ++i) nidx[i] = min(n0 + nb + i, NN - 1);

    float acc[4][8];
    #pragma unroll
    for (int i = 0; i < 4; ++i)
        #pragma unroll
        for (int j = 0; j < 8; ++j) acc[i][j] = 0.0f;

    #pragma unroll 4
    for (int kk = 0; kk < 2 * HD; ++kk) {
        const float4* wp = reinterpret_cast<const float4*>(Wh1 + (size_t)kk * HD + ch0);
        const float4 b0 = wp[0], b1 = wp[1];
        const float bb[8] = {b0.x,b0.y,b0.z,b0.w,b1.x,b1.y,b1.z,b1.w};
        #pragma unroll
        for (int i = 0; i < 4; ++i) {
            const float a = (kk < HD) ? h[(size_t)nidx[i]*HD + kk]
                                      : msg_agg[(size_t)nidx[i]*HD + (kk - HD)];
            #pragma unroll
            for (int j = 0; j < 8; ++j) acc[i][j] += a * bb[j];
        }
    }
    {
        const float4* bp = reinterpret_cast<const float4*>(bh1 + ch0);
        const float4 c0v = bp[0], c1v = bp[1];
        const float bias[8] = {c0v.x,c0v.y,c0v.z,c0v.w,c1v.x,c1v.y,c1v.z,c1v.w};
        #pragma unroll
        for (int i = 0; i < 4; ++i)
            #pragma unroll
            for (int j = 0; j < 8; ++j)
                sT[nb+i][ch0+j] = silu_f(acc[i][j] + bias[j]);
    }
    __syncthreads();

    #pragma unroll
    for (int i = 0; i < 4; ++i)
        #pragma unroll
        for (int j = 0; j < 8; ++j) acc[i][j] = 0.0f;
    #pragma unroll 4
    for (int kk = 0; kk < HD; ++kk) {
        const float4* wp = reinterpret_cast<const float4*>(Wh2 + (size_t)kk * HD + ch0);
        const float4 b0 = wp[0], b1 = wp[1];
        const float bb[8] = {b0.x,b0.y,b0.z,b0.w,b1.x,b1.y,b1.z,b1.w};
        #pragma unroll
        for (int i = 0; i < 4; ++i) {
            const float a = sT[nb+i][kk];
            #pragma unroll
            for (int j = 0; j < 8; ++j) acc[i][j] += a * bb[j];
        }
    }
    {
        const float4* bp = reinterpret_cast<const float4*>(bh2 + ch0);
        const float4 c0v = bp[0], c1v = bp[1];
        const float bias[8] = {c0v.x,c0v.y,c0v.z,c0v.w,c1v.x,c1v.y,c1v.z,c1v.w};
        #pragma unroll
        for (int i = 0; i < 4; ++i) {
            const int n = n0 + nb + i;
            if (n < NN) {
                #pragma unroll
                for (int j = 0; j < 8; ++j)
                    out_h[(size_t)n*HD + ch0 + j] =
                        h[(size_t)n*HD + ch0 + j] + acc[i][j] + bias[j];
            }
        }
    }
}

extern "C" void kernel_launch(void* const* d_in, const int* in_sizes, int n_in,
                              void* d_out, int out_size, void* d_ws, size_t ws_size,
                              hipStream_t stream)
{
    const float* h     = (const float*)d_in[0];
    const float* x     = (const float*)d_in[1];
    const int*   ei    = (const int*)d_in[2];
    const float* eattr = (const float*)d_in[3];
    const int*   fmask = (const int*)d_in[4];
    const float* We1   = (const float*)d_in[5];
    const float* be1   = (const float*)d_in[6];
    const float* We2   = (const float*)d_in[7];
    const float* be2   = (const float*)d_in[8];
    const float* Wx1   = (const float*)d_in[9];
    const float* bx1   = (const float*)d_in[10];
    const float* Wx2   = (const float*)d_in[11];
    const float* bx2   = (const float*)d_in[12];
    const float* Wh1   = (const float*)d_in[13];
    const float* bh1   = (const float*)d_in[14];
    const float* Wh2   = (const float*)d_in[15];
    const float* bh2   = (const float*)d_in[16];

    // workspace layout (fp32-aligned regions)
    float* msg   = (float*)d_ws;                         // [NN,HD]   10.24 MB
    float* coord = msg + (size_t)NN * HD;                // [NN,3]    240 KB
    unsigned short* hb   = (unsigned short*)(coord + (size_t)NN * 3);
    unsigned short* PWe1 = hb + (size_t)NN * HD;         // 36864 elems
    unsigned short* PWe2 = PWe1 + (size_t)(KP1/32) * 8 * 512;
    unsigned short* PWx1 = PWe2 + (size_t)4 * 8 * 512;

    float* out_h = (float*)d_out;
    float* out_x = out_h + (size_t)NN * HD;

    hipMemsetAsync(d_ws, 0, (size_t)NN * (HD + 3) * sizeof(float), stream);
    egnn_prep_kernel<<<1024, 256, 0, stream>>>(h, We1, We2, Wx1, hb, PWe1, PWe2, PWx1);
    egnn_edge_kernel<<<NE / 64, 256, 0, stream>>>(
        hb, x, ei, eattr, PWe1, be1, PWe2, be2, PWx1, bx1, Wx2, bx2, msg, coord);
    egnn_node_kernel<<<(NN + 63) / 64, 256, 0, stream>>>(
        h, x, fmask, Wh1, bh1, Wh2, bh2, msg, coord, out_h, out_x);
}

// Round 3
// 522.571 us; speedup vs baseline: 3.2919x; 1.1287x over previous
//
#include <hip/hip_runtime.h>
#include <hip/hip_bf16.h>
#include <math.h>

#define NN   20000
#define NE   640000
#define HD   128
#define EDIM 16
#define KIN  273    // 2H + 1 + ED
#define KP1  288    // KIN padded to 9*32
#define P1   296    // e_in LDS pitch (ushorts): 592 B
#define P2   136    // t1/m LDS pitch (ushorts): 272 B
#define PR   69     // pRed pitch (dwords): (t*69+cc)%32 = (5t+cc)%32 -> 2-way max

typedef __bf16 bf16x8 __attribute__((ext_vector_type(8)));
typedef float  f32x4  __attribute__((ext_vector_type(4)));

// fast silu: __expf -> v_mul+v_exp; rcp -> v_rcp_f32 (~1 ulp, invisible in bf16)
__device__ __forceinline__ float silu_f(float v) {
    const float e = __expf(-v);
    return v * __builtin_amdgcn_rcpf(1.0f + e);
}
// fast tanh: 1 - 2/(e^{2s}+1); saturates correctly at +/-inf
__device__ __forceinline__ float tanh_f(float s) {
    const float e = __expf(2.0f * s);
    return 1.0f - 2.0f * __builtin_amdgcn_rcpf(e + 1.0f);
}

__device__ __forceinline__ unsigned short f2bf(float f) {
    __bf16 b = (__bf16)f;
    return __builtin_bit_cast(unsigned short, b);
}
__device__ __forceinline__ float bf2f(unsigned short u) {
    __bf16 b = __builtin_bit_cast(__bf16, u);
    return (float)b;
}

// -------------------- Prep: h->bf16, pack W into MFMA B-frag order ----------
__device__ __forceinline__ void pack_one(const float* __restrict__ W, int Kreal,
                                         unsigned short* __restrict__ P, int idx) {
    const int f    = idx >> 9;
    const int r    = idx & 511;
    const int lane = r >> 3;
    const int j    = r & 7;
    const int kb   = f >> 3;
    const int nb   = f & 7;
    const int k    = kb * 32 + (lane >> 4) * 8 + j;
    const int n    = nb * 16 + (lane & 15);
    const float v  = (k < Kreal) ? W[(size_t)k * HD + n] : 0.0f;
    P[idx] = f2bf(v);
}

__global__ void egnn_prep_kernel(
    const float* __restrict__ h,
    const float* __restrict__ We1, const float* __restrict__ We2,
    const float* __restrict__ Wx1,
    unsigned short* __restrict__ hb,
    unsigned short* __restrict__ PWe1, unsigned short* __restrict__ PWe2,
    unsigned short* __restrict__ PWx1)
{
    const size_t NH = (size_t)NN * HD;
    const size_t S1 = (size_t)(KP1 / 32) * 8 * 512;
    const size_t S2 = (size_t)4 * 8 * 512;
    const size_t S3 = S2;
    const size_t total  = NH + S1 + S2 + S3;
    const size_t stride = (size_t)gridDim.x * blockDim.x;
    for (size_t i = (size_t)blockIdx.x * blockDim.x + threadIdx.x; i < total; i += stride) {
        if (i < NH) {
            hb[i] = f2bf(h[i]);
        } else if (i < NH + S1) {
            pack_one(We1, KIN, PWe1, (int)(i - NH));
        } else if (i < NH + S1 + S2) {
            pack_one(We2, HD, PWe2, (int)(i - NH - S1));
        } else {
            pack_one(Wx1, HD, PWx1, (int)(i - NH - S1 - S2));
        }
    }
}

// -------------------- Edge kernel (MFMA) --------------------
__global__ __launch_bounds__(256, 2) void egnn_edge_kernel(
    const unsigned short* __restrict__ hb, const float* __restrict__ x,
    const int* __restrict__ ei, const float* __restrict__ eattr,
    const unsigned short* __restrict__ PWe1, const float* __restrict__ be1,
    const unsigned short* __restrict__ PWe2, const float* __restrict__ be2,
    const unsigned short* __restrict__ PWx1, const float* __restrict__ bx1,
    const float* __restrict__ Wx2, const float* __restrict__ bx2,
    float* __restrict__ msg_agg, float* __restrict__ coord_agg)
{
    __shared__ __align__(16) unsigned short eA[64 * P1];
    __shared__ __align__(16) unsigned short sT[64 * P2];
    __shared__ __align__(16) unsigned short sM[64 * P2];
    __shared__ int   sSrc[64], sDst[64];
    __shared__ float sDiff[64][3];
    __shared__ float sDist[64];
    __shared__ float sW[64];

    const int t  = threadIdx.x;
    const int e0 = blockIdx.x * 64;

    if (t < 64) {
        const int e = e0 + t;
        const int s = ei[e];
        const int d = ei[NE + e];
        sSrc[t] = s; sDst[t] = d;
        const float dx = x[s*3+0] - x[d*3+0];
        const float dy = x[s*3+1] - x[d*3+1];
        const float dz = x[s*3+2] - x[d*3+2];
        sDiff[t][0] = dx; sDiff[t][1] = dy; sDiff[t][2] = dz;
        sDist[t] = (dx*dx + dy*dy + dz*dz) * 0.01f;
    }
    __syncthreads();

    {
        const int eL = t >> 2, q = t & 3;
        const unsigned short* hs = hb + (size_t)sSrc[eL] * HD + q * 32;
        const unsigned short* hd = hb + (size_t)sDst[eL] * HD + q * 32;
        uint4* dsts = (uint4*)&eA[eL * P1 + q * 32];
        uint4* dstd = (uint4*)&eA[eL * P1 + 128 + q * 32];
        #pragma unroll
        for (int v = 0; v < 4; ++v) dsts[v] = ((const uint4*)hs)[v];
        #pragma unroll
        for (int v = 0; v < 4; ++v) dstd[v] = ((const uint4*)hd)[v];
        #pragma unroll
        for (int jj = 0; jj < 8; ++jj) {
            const int kg = 256 + q * 8 + jj;
            float v = 0.0f;
            if (kg == 256)     v = sDist[eL];
            else if (kg < KIN) v = eattr[(size_t)(e0 + eL) * EDIM + (kg - 257)];
            eA[eL * P1 + kg] = f2bf(v);
        }
    }
    __syncthreads();

    const int lane = t & 63;
    const int w    = t >> 6;
    const int quad = lane >> 4;
    const int l16  = lane & 15;

    // ---- GEMM1 ----
    f32x4 acc1[4][2];
    #pragma unroll
    for (int mb = 0; mb < 4; ++mb)
        #pragma unroll
        for (int nt = 0; nt < 2; ++nt) acc1[mb][nt] = (f32x4){0.f,0.f,0.f,0.f};

    for (int kb = 0; kb < 9; ++kb) {
        bf16x8 a[4], b[2];
        #pragma unroll
        for (int mb = 0; mb < 4; ++mb)
            a[mb] = *(const bf16x8*)&eA[(mb * 16 + l16) * P1 + kb * 32 + quad * 8];
        #pragma unroll
        for (int nt = 0; nt < 2; ++nt) {
            const int nb = w * 2 + nt;
            b[nt] = *(const bf16x8*)&PWe1[((kb * 8 + nb) * 64 + lane) * 8];
        }
        #pragma unroll
        for (int mb = 0; mb < 4; ++mb)
            #pragma unroll
            for (int nt = 0; nt < 2; ++nt)
                acc1[mb][nt] = __builtin_amdgcn_mfma_f32_16x16x32_bf16(
                    a[mb], b[nt], acc1[mb][nt], 0, 0, 0);
    }
    #pragma unroll
    for (int nt = 0; nt < 2; ++nt) {
        const int col = (w * 2 + nt) * 16 + l16;
        const float bias = be1[col];
        #pragma unroll
        for (int mb = 0; mb < 4; ++mb)
            #pragma unroll
            for (int r = 0; r < 4; ++r) {
                const int row = mb * 16 + quad * 4 + r;
                sT[row * P2 + col] = f2bf(silu_f(acc1[mb][nt][r] + bias));
            }
    }
    __syncthreads();

    // ---- GEMM2 ----
    f32x4 acc2[4][2];
    #pragma unroll
    for (int mb = 0; mb < 4; ++mb)
        #pragma unroll
        for (int nt = 0; nt < 2; ++nt) acc2[mb][nt] = (f32x4){0.f,0.f,0.f,0.f};
    for (int kb = 0; kb < 4; ++kb) {
        bf16x8 a[4], b[2];
        #pragma unroll
        for (int mb = 0; mb < 4; ++mb)
            a[mb] = *(const bf16x8*)&sT[(mb * 16 + l16) * P2 + kb * 32 + quad * 8];
        #pragma unroll
        for (int nt = 0; nt < 2; ++nt) {
            const int nb = w * 2 + nt;
            b[nt] = *(const bf16x8*)&PWe2[((kb * 8 + nb) * 64 + lane) * 8];
        }
        #pragma unroll
        for (int mb = 0; mb < 4; ++mb)
            #pragma unroll
            for (int nt = 0; nt < 2; ++nt)
                acc2[mb][nt] = __builtin_amdgcn_mfma_f32_16x16x32_bf16(
                    a[mb], b[nt], acc2[mb][nt], 0, 0, 0);
    }
    #pragma unroll
    for (int nt = 0; nt < 2; ++nt) {
        const int col = (w * 2 + nt) * 16 + l16;
        const float bias = be2[col];
        #pragma unroll
        for (int mb = 0; mb < 4; ++mb)
            #pragma unroll
            for (int r = 0; r < 4; ++r) {
                const int row = mb * 16 + quad * 4 + r;
                sM[row * P2 + col] = f2bf(silu_f(acc2[mb][nt][r] + bias));
            }
    }
    __syncthreads();

    // ---- msg scatter (overlaps GEMM3) ----
    {
        const int ch    = t & 127;
        const int ebase = t >> 7;
        #pragma unroll
        for (int it = 0; it < 32; ++it) {
            const int e = ebase + it * 2;
            atomicAdd(&msg_agg[(size_t)sDst[e] * HD + ch], bf2f(sM[e * P2 + ch]));
        }
    }

    // ---- GEMM3 + coord_w ----
    f32x4 acc3[4][2];
    #pragma unroll
    for (int mb = 0; mb < 4; ++mb)
        #pragma unroll
        for (int nt = 0; nt < 2; ++nt) acc3[mb][nt] = (f32x4){0.f,0.f,0.f,0.f};
    for (int kb = 0; kb < 4; ++kb) {
        bf16x8 a[4], b[2];
        #pragma unroll
        for (int mb = 0; mb < 4; ++mb)
            a[mb] = *(const bf16x8*)&sM[(mb * 16 + l16) * P2 + kb * 32 + quad * 8];
        #pragma unroll
        for (int nt = 0; nt < 2; ++nt) {
            const int nb = w * 2 + nt;
            b[nt] = *(const bf16x8*)&PWx1[((kb * 8 + nb) * 64 + lane) * 8];
        }
        #pragma unroll
        for (int mb = 0; mb < 4; ++mb)
            #pragma unroll
            for (int nt = 0; nt < 2; ++nt)
                acc3[mb][nt] = __builtin_amdgcn_mfma_f32_16x16x32_bf16(
                    a[mb], b[nt], acc3[mb][nt], 0, 0, 0);
    }
    {
        float* pRed = reinterpret_cast<float*>(eA);   // [64][PR] fp32
        float bias[2], wx[2];
        #pragma unroll
        for (int nt = 0; nt < 2; ++nt) {
            const int col = (w * 2 + nt) * 16 + l16;
            bias[nt] = bx1[col];
            wx[nt]   = Wx2[col];
        }
        #pragma unroll
        for (int mb = 0; mb < 4; ++mb)
            #pragma unroll
            for (int r = 0; r < 4; ++r) {
                const int row = mb * 16 + quad * 4 + r;
                float p = 0.0f;
                #pragma unroll
                for (int nt = 0; nt < 2; ++nt)
                    p += silu_f(acc3[mb][nt][r] + bias[nt]) * wx[nt];
                pRed[row * PR + w * 16 + l16] = p;
            }
    }
    __syncthreads();
    if (t < 64) {
        const float* pRed = reinterpret_cast<const float*>(eA);
        float s = bx2[0];
        #pragma unroll 8
        for (int cc = 0; cc < 64; ++cc) s += pRed[t * PR + cc];
        sW[t] = tanh_f(s);
    }
    __syncthreads();

    if (t < 192) {
        const int e  = t / 3;
        const int d3 = t - e * 3;
        atomicAdd(&coord_agg[(size_t)sDst[e] * 3 + d3], sDiff[e][d3] * sW[e]);
    }
}

// -------------------- Node kernel --------------------
__global__ __launch_bounds__(256, 4) void egnn_node_kernel(
    const float* __restrict__ h, const float* __restrict__ x,
    const int* __restrict__ fixed_mask,
    const float* __restrict__ Wh1, const float* __restrict__ bh1,
    const float* __restrict__ Wh2, const float* __restrict__ bh2,
    const float* __restrict__ msg_agg, const float* __restrict__ coord_agg,
    float* __restrict__ out_h, float* __restrict__ out_x)
{
    __shared__ float sT[64][HD + 4];
    const int t  = threadIdx.x;
    const int n0 = blockIdx.x * 64;
    const int c = t & 15, r = t >> 4;
    const int ch0 = c * 8, nb = r * 4;

    if (t < 192) {
        const int ln = t / 3, d3 = t - ln * 3;
        const int n  = n0 + ln;
        if (n < NN) {
            const float add = (fixed_mask[n] != 0) ? 0.0f : coord_agg[(size_t)n*3 + d3];
            out_x[(size_t)n*3 + d3] = x[(size_t)n*3 + d3] + add;
        }
    }

    int nidx[4];
    #pragma unroll
    for (int i = 0; i < 4; ++i) nidx[i] = min(n0 + nb + i, NN - 1);

    float acc[4][8];
    #pragma unroll
    for (int i = 0; i < 4; ++i)
        #pragma unroll
        for (int j = 0; j < 8; ++j) acc[i][j] = 0.0f;

    #pragma unroll 4
    for (int kk = 0; kk < 2 * HD; ++kk) {
        const float4* wp = reinterpret_cast<const float4*>(Wh1 + (size_t)kk * HD + ch0);
        const float4 b0 = wp[0], b1 = wp[1];
        const float bb[8] = {b0.x,b0.y,b0.z,b0.w,b1.x,b1.y,b1.z,b1.w};
        #pragma unroll
        for (int i = 0; i < 4; ++i) {
            const float a = (kk < HD) ? h[(size_t)nidx[i]*HD + kk]
                                      : msg_agg[(size_t)nidx[i]*HD + (kk - HD)];
            #pragma unroll
            for (int j = 0; j < 8; ++j) acc[i][j] += a * bb[j];
        }
    }
    {
        const float4* bp = reinterpret_cast<const float4*>(bh1 + ch0);
        const float4 c0v = bp[0], c1v = bp[1];
        const float bias[8] = {c0v.x,c0v.y,c0v.z,c0v.w,c1v.x,c1v.y,c1v.z,c1v.w};
        #pragma unroll
        for (int i = 0; i < 4; ++i)
            #pragma unroll
            for (int j = 0; j < 8; ++j)
                sT[nb+i][ch0+j] = silu_f(acc[i][j] + bias[j]);
    }
    __syncthreads();

    #pragma unroll
    for (int i = 0; i < 4; ++i)
        #pragma unroll
        for (int j = 0; j < 8; ++j) acc[i][j] = 0.0f;
    #pragma unroll 4
    for (int kk = 0; kk < HD; ++kk) {
        const float4* wp = reinterpret_cast<const float4*>(Wh2 + (size_t)kk * HD + ch0);
        const float4 b0 = wp[0], b1 = wp[1];
        const float bb[8] = {b0.x,b0.y,b0.z,b0.w,b1.x,b1.y,b1.z,b1.w};
        #pragma unroll
        for (int i = 0; i < 4; ++i) {
            const float a = sT[nb+i][kk];
            #pragma unroll
            for (int j = 0; j < 8; ++j) acc[i][j] += a * bb[j];
        }
    }
    {
        const float4* bp = reinterpret_cast<const float4*>(bh2 + ch0);
        const float4 c0v = bp[0], c1v = bp[1];
        const float bias[8] = {c0v.x,c0v.y,c0v.z,c0v.w,c1v.x,c1v.y,c1v.z,c1v.w};
        #pragma unroll
        for (int i = 0; i < 4; ++i) {
            const int n = n0 + nb + i;
            if (n < NN) {
                #pragma unroll
                for (int j = 0; j < 8; ++j)
                    out_h[(size_t)n*HD + ch0 + j] =
                        h[(size_t)n*HD + ch0 + j] + acc[i][j] + bias[j];
            }
        }
    }
}

extern "C" void kernel_launch(void* const* d_in, const int* in_sizes, int n_in,
                              void* d_out, int out_size, void* d_ws, size_t ws_size,
                              hipStream_t stream)
{
    const float* h     = (const float*)d_in[0];
    const float* x     = (const float*)d_in[1];
    const int*   ei    = (const int*)d_in[2];
    const float* eattr = (const float*)d_in[3];
    const int*   fmask = (const int*)d_in[4];
    const float* We1   = (const float*)d_in[5];
    const float* be1   = (const float*)d_in[6];
    const float* We2   = (const float*)d_in[7];
    const float* be2   = (const float*)d_in[8];
    const float* Wx1   = (const float*)d_in[9];
    const float* bx1   = (const float*)d_in[10];
    const float* Wx2   = (const float*)d_in[11];
    const float* bx2   = (const float*)d_in[12];
    const float* Wh1   = (const float*)d_in[13];
    const float* bh1   = (const float*)d_in[14];
    const float* Wh2   = (const float*)d_in[15];
    const float* bh2   = (const float*)d_in[16];

    float* msg   = (float*)d_ws;
    float* coord = msg + (size_t)NN * HD;
    unsigned short* hb   = (unsigned short*)(coord + (size_t)NN * 3);
    unsigned short* PWe1 = hb + (size_t)NN * HD;
    unsigned short* PWe2 = PWe1 + (size_t)(KP1/32) * 8 * 512;
    unsigned short* PWx1 = PWe2 + (size_t)4 * 8 * 512;

    float* out_h = (float*)d_out;
    float* out_x = out_h + (size_t)NN * HD;

    hipMemsetAsync(d_ws, 0, (size_t)NN * (HD + 3) * sizeof(float), stream);
    egnn_prep_kernel<<<1024, 256, 0, stream>>>(h, We1, We2, Wx1, hb, PWe1, PWe2, PWx1);
    egnn_edge_kernel<<<NE / 64, 256, 0, stream>>>(
        hb, x, ei, eattr, PWe1, be1, PWe2, be2, PWx1, bx1, Wx2, bx2, msg, coord);
    egnn_node_kernel<<<(NN + 63) / 64, 256, 0, stream>>>(
        h, x, fmask, Wh1, bh1, Wh2, bh2, msg, coord, out_h, out_x);
}